// Round 3
// baseline (192.579 us; speedup 1.0000x reference)
//
#include <hip/hip_runtime.h>

// Problem constants
#define H_ROWS 4096
#define IN_F   4096
#define OUT_F  4096

typedef __bf16 bf16;
typedef __bf16 bf16x4 __attribute__((ext_vector_type(4)));
typedef __bf16 bf16x8 __attribute__((ext_vector_type(8)));
typedef float  f32x4  __attribute__((ext_vector_type(4)));

// ---------------------------------------------------------------------------
// Kernel 1: R3 reduce, restored verbatim (proven 48 µs / 62% occ / 1.48 TB/s).
// R4 post-mortem: wave-per-row + 2048 blocks REGRESSED to 56 µs — the winning
// ingredient in R3 is fine-grained block retirement (8192 blocks, backfill),
// not barrier removal. Per-wave ILP is a measured null lever (R1/R2: 57 µs
// pinned). Do not touch this kernel again without new counter evidence.
// ---------------------------------------------------------------------------
__global__ __launch_bounds__(256) void reduce_kernel(
    const float* __restrict__ x, const float* __restrict__ w,
    bf16* __restrict__ xs, bf16* __restrict__ wsT)
{
    __shared__ float lds[1024];
    const int bid = blockIdx.x;
    const float* __restrict__ src = (bid & 1) ? w : x;
    bf16* __restrict__ dst = (bid & 1) ? wsT : xs;
    const int r   = bid >> 1;            // row 0..4095
    const int tid = threadIdx.x;

    const float4* __restrict__ s = (const float4*)src + r * (IN_F / 4);
    float4 a0 = s[tid];
    float4 a1 = s[tid + 256];
    float4 a2 = s[tid + 512];
    float4 a3 = s[tid + 768];
    float4 acc;
    acc.x = (a0.x + a1.x) + (a2.x + a3.x);
    acc.y = (a0.y + a1.y) + (a2.y + a3.y);
    acc.z = (a0.z + a1.z) + (a2.z + a3.z);
    acc.w = (a0.w + a1.w) + (a2.w + a3.w);

    ((float4*)lds)[tid] = acc;
    __syncthreads();

    if (tid < 64) {
        float4 b0 = ((const float4*)lds)[tid];
        float4 b1 = ((const float4*)lds)[tid + 64];
        float4 b2 = ((const float4*)lds)[tid + 128];
        float4 b3 = ((const float4*)lds)[tid + 192];
        float4 t;
        t.x = (b0.x + b1.x) + (b2.x + b3.x);
        t.y = (b0.y + b1.y) + (b2.y + b3.y);
        t.z = (b0.z + b1.z) + (b2.z + b3.z);
        t.w = (b0.w + b1.w) + (b2.w + b3.w);
        bf16x4 o;
        o[0] = (bf16)t.x; o[1] = (bf16)t.y; o[2] = (bf16)t.z; o[3] = (bf16)t.w;
        *(bf16x4*)(dst + r * 256 + tid * 4) = o;
    }
}

// ---------------------------------------------------------------------------
// Kernel 2 (R6): NT GEMM  out[m][n] = sum_k A[m][k]*B[n][k] + bias[n]
//   A = xs (M=4096,K=256) bf16 RM; B = wsT (N=4096,K=256) bf16 RM.
// Changes vs BK=32 version:
//   - BK=64: 4 K-steps, 8 barriers total (was 16) — barrier drain dominates
//     at K this small.
//   - T2 XOR swizzle (rule #21: both-sides-or-neither with global_load_lds):
//     LDS dest stays LINEAR (ch*16B, lane-contiguous as gload_lds requires);
//     the GLOBAL source chunk is pre-permuted kc^(row&7); the ds_read applies
//     the same XOR. Old layout: 64B rows -> 16 lanes on 8 banks = 8-way
//     conflict (2.94x). New: (jc^r7)*4+j covers all 32 banks at 2-way = free.
//   - Fragments loaded per-u half (8 live b128 regs, not 16) to hold VGPR
//     ~120 -> 4 blocks/CU unchanged.
// Epilogue/acc layout byte-identical to the verified version (absmax 0.0625).
// ---------------------------------------------------------------------------
__global__ __launch_bounds__(256) void gemm_bt_kernel(
    const bf16* __restrict__ A, const bf16* __restrict__ B,
    const float* __restrict__ bias, float* __restrict__ out)
{
    __shared__ bf16 As[128 * 64];   // 16 KB
    __shared__ bf16 Bs[128 * 64];   // 16 KB

    const int m0   = blockIdx.y * 128;
    const int n0   = blockIdx.x * 128;
    const int tid  = threadIdx.x;
    const int lane = tid & 63;
    const int w    = tid >> 6;
    const int wm   = (w & 1) * 64;
    const int wn   = (w >> 1) * 64;
    const int l15  = lane & 15;
    const int quad = lane >> 4;
    const int r7   = l15 & 7;       // row&7 for all fragment rows

    f32x4 acc[4][4] = {};

    for (int kk = 0; kk < 4; ++kk) {
        const int k0 = kk * 64;
        #pragma unroll
        for (int c = 0; c < 4; ++c) {
            const int ch  = c * 256 + tid;     // 16B chunk id 0..1023
            const int row = ch >> 3;           // 0..127
            const int kc  = ch & 7;            // physical chunk within row
            const int kcs = kc ^ (row & 7);    // pre-swizzled source chunk
            const bf16* ga = A + (m0 + row) * 256 + k0 + kcs * 8;
            const bf16* gb = B + (n0 + row) * 256 + k0 + kcs * 8;
            __builtin_amdgcn_global_load_lds(
                (const __attribute__((address_space(1))) void*)ga,
                (__attribute__((address_space(3))) void*)(As + ch * 8), 16, 0, 0);
            __builtin_amdgcn_global_load_lds(
                (const __attribute__((address_space(1))) void*)gb,
                (__attribute__((address_space(3))) void*)(Bs + ch * 8), 16, 0, 0);
        }
        __syncthreads();

        #pragma unroll
        for (int u = 0; u < 2; ++u) {
            const int jc = u * 4 + quad;       // logical 16B chunk (8 bf16)
            bf16x8 af[4], bfr[4];
            #pragma unroll
            for (int t = 0; t < 4; ++t) {
                const int ra = wm + t * 16 + l15;   // A row (ra&7 == r7)
                const int rb = wn + t * 16 + l15;   // B row
                af[t]  = *(const bf16x8*)(As + ra * 64 + (jc ^ r7) * 8);
                bfr[t] = *(const bf16x8*)(Bs + rb * 64 + (jc ^ r7) * 8);
            }
            #pragma unroll
            for (int mt = 0; mt < 4; ++mt)
                #pragma unroll
                for (int nt = 0; nt < 4; ++nt)
                    acc[mt][nt] = __builtin_amdgcn_mfma_f32_16x16x32_bf16(
                        af[mt], bfr[nt], acc[mt][nt], 0, 0, 0);
        }
        __syncthreads();
    }

    #pragma unroll
    for (int nt = 0; nt < 4; ++nt) {
        const int col = n0 + wn + nt * 16 + l15;
        const float bv = bias[col];
        #pragma unroll
        for (int mt = 0; mt < 4; ++mt) {
            const int rbase = m0 + wm + mt * 16 + quad * 4;
            #pragma unroll
            for (int r = 0; r < 4; ++r)
                out[(rbase + r) * OUT_F + col] = acc[mt][nt][r] + bv;
        }
    }
}

extern "C" void kernel_launch(void* const* d_in, const int* in_sizes, int n_in,
                              void* d_out, int out_size, void* d_ws, size_t ws_size,
                              hipStream_t stream)
{
    const float* x      = (const float*)d_in[0];  // (4096, 4096)
    const float* weight = (const float*)d_in[1];  // (4096, 4096)
    const float* bias   = (const float*)d_in[2];  // (4096,)
    float* out = (float*)d_out;                   // (4096, 4096) f32

    bf16* xs  = (bf16*)d_ws;                      // 4096*256 bf16 = 2 MB
    bf16* wsT = xs + 4096 * 256;                  // 4096*256 bf16 = 2 MB

    reduce_kernel<<<8192, 256, 0, stream>>>(x, weight, xs, wsT);
    gemm_bt_kernel<<<dim3(32, 32), 256, 0, stream>>>(xs, wsT, bias, out);
}

// Round 4
// 189.161 us; speedup vs baseline: 1.0181x; 1.0181x over previous
//
#include <hip/hip_runtime.h>

// Problem constants
#define H_ROWS 4096
#define IN_F   4096
#define OUT_F  4096

typedef __bf16 bf16;
typedef __bf16 bf16x4 __attribute__((ext_vector_type(4)));
typedef __bf16 bf16x8 __attribute__((ext_vector_type(8)));
typedef float  f32x4  __attribute__((ext_vector_type(4)));

// ---------------------------------------------------------------------------
// Kernel 1: R3 reduce, verbatim (proven 48 µs / 62% occ / 1.48 TB/s HBM +
// L3-served remainder). R4 post-mortem: wave-per-row + 2048 blocks regressed
// to 56 µs — the winning ingredient is fine-grained block retirement (8192
// blocks, backfill). Per-wave ILP is a measured null lever (R1/R2 pinned).
// Do not touch without new counter evidence.
// ---------------------------------------------------------------------------
__global__ __launch_bounds__(256) void reduce_kernel(
    const float* __restrict__ x, const float* __restrict__ w,
    bf16* __restrict__ xs, bf16* __restrict__ wsT)
{
    __shared__ float lds[1024];
    const int bid = blockIdx.x;
    const float* __restrict__ src = (bid & 1) ? w : x;
    bf16* __restrict__ dst = (bid & 1) ? wsT : xs;
    const int r   = bid >> 1;            // row 0..4095
    const int tid = threadIdx.x;

    const float4* __restrict__ s = (const float4*)src + r * (IN_F / 4);
    float4 a0 = s[tid];
    float4 a1 = s[tid + 256];
    float4 a2 = s[tid + 512];
    float4 a3 = s[tid + 768];
    float4 acc;
    acc.x = (a0.x + a1.x) + (a2.x + a3.x);
    acc.y = (a0.y + a1.y) + (a2.y + a3.y);
    acc.z = (a0.z + a1.z) + (a2.z + a3.z);
    acc.w = (a0.w + a1.w) + (a2.w + a3.w);

    ((float4*)lds)[tid] = acc;
    __syncthreads();

    if (tid < 64) {
        float4 b0 = ((const float4*)lds)[tid];
        float4 b1 = ((const float4*)lds)[tid + 64];
        float4 b2 = ((const float4*)lds)[tid + 128];
        float4 b3 = ((const float4*)lds)[tid + 192];
        float4 t;
        t.x = (b0.x + b1.x) + (b2.x + b3.x);
        t.y = (b0.y + b1.y) + (b2.y + b3.y);
        t.z = (b0.z + b1.z) + (b2.z + b3.z);
        t.w = (b0.w + b1.w) + (b2.w + b3.w);
        bf16x4 o;
        o[0] = (bf16)t.x; o[1] = (bf16)t.y; o[2] = (bf16)t.z; o[3] = (bf16)t.w;
        *(bf16x4*)(dst + r * 256 + tid * 4) = o;
    }
}

// ---------------------------------------------------------------------------
// Kernel 2 (R7): NT GEMM  out[m][n] = sum_k A[m][k]*B[n][k] + bias[n]
//   A = xs (M=4096,K=256) bf16 RM; B = wsT (N=4096,K=256) bf16 RM.
// Back to the verified BK=32 m97 structure. R6 post-mortem: the BK=64
// "bank-conflict fix" regressed ~6 µs — re-derivation shows the BK=32
// fragment ds_read_b128 is already perfectly bank-BALANCED (8 lanes on each
// of the 8 four-bank groups = minimum serialization; SQ_LDS_BANK_CONFLICT=0),
// so the swizzle fixed nothing and the 32KB single-buffer LDS cut residency.
// This round's change: 2-phase double-buffer (T3-min). Grid is 1024 blocks
// = 4/CU, ALL co-resident, so 32 KB LDS (2x8KB As + 2x8KB Bs) costs zero
// occupancy (160/32=5 >= 4). One barrier per K-step (8 total, was 16);
// STAGE(kk+1) issued before ds_read+MFMA of kk, so the ~200-300cy L2 load
// latency hides under compute instead of being exposed at every drain.
// ---------------------------------------------------------------------------
__global__ __launch_bounds__(256) void gemm_bt_kernel(
    const bf16* __restrict__ A, const bf16* __restrict__ B,
    const float* __restrict__ bias, float* __restrict__ out)
{
    __shared__ bf16 As[2][128 * 32];   // 2 x 8 KB
    __shared__ bf16 Bs[2][128 * 32];   // 2 x 8 KB

    const int m0   = blockIdx.y * 128;
    const int n0   = blockIdx.x * 128;
    const int tid  = threadIdx.x;
    const int lane = tid & 63;
    const int w    = tid >> 6;
    const int wm   = (w & 1) * 64;
    const int wn   = (w >> 1) * 64;
    const int l15  = lane & 15;
    const int quad = lane >> 4;

    // Stage K-step kk into buffer b: 512 x 16B chunks, lane-contiguous LDS
    // dest as global_load_lds requires.
    #define STAGE(b, kk)                                                      \
    {                                                                         \
        const int k0 = (kk) * 32;                                             \
        _Pragma("unroll")                                                     \
        for (int c = 0; c < 2; ++c) {                                         \
            const int chunk = c * 256 + tid;                                  \
            const int row   = chunk >> 2;                                     \
            const int kc    = chunk & 3;                                      \
            const bf16* ga = A + (m0 + row) * 256 + k0 + kc * 8;              \
            const bf16* gb = B + (n0 + row) * 256 + k0 + kc * 8;              \
            __builtin_amdgcn_global_load_lds(                                 \
                (const __attribute__((address_space(1))) void*)ga,            \
                (__attribute__((address_space(3))) void*)(As[b] + chunk * 8), \
                16, 0, 0);                                                    \
            __builtin_amdgcn_global_load_lds(                                 \
                (const __attribute__((address_space(1))) void*)gb,            \
                (__attribute__((address_space(3))) void*)(Bs[b] + chunk * 8), \
                16, 0, 0);                                                    \
        }                                                                     \
    }

    f32x4 acc[4][4] = {};

    STAGE(0, 0);

    int buf = 0;
    for (int kk = 0; kk < 8; ++kk) {
        // Barrier (compiler drains vmcnt before s_barrier): staging(kk) into
        // As[buf]/Bs[buf] is now visible, and every wave's reads of the
        // OTHER buffer (iter kk-1) are done, so it is safe to overwrite.
        __syncthreads();
        if (kk < 7) STAGE(buf ^ 1, kk + 1);   // loads fly during MFMA below

        bf16x8 af[4], bfr[4];
        #pragma unroll
        for (int t = 0; t < 4; ++t) {
            af[t]  = *(const bf16x8*)(As[buf] + (wm + t * 16 + l15) * 32 + quad * 8);
            bfr[t] = *(const bf16x8*)(Bs[buf] + (wn + t * 16 + l15) * 32 + quad * 8);
        }
        #pragma unroll
        for (int mt = 0; mt < 4; ++mt)
            #pragma unroll
            for (int nt = 0; nt < 4; ++nt)
                acc[mt][nt] = __builtin_amdgcn_mfma_f32_16x16x32_bf16(
                    af[mt], bfr[nt], acc[mt][nt], 0, 0, 0);
        buf ^= 1;
    }
    #undef STAGE

    #pragma unroll
    for (int nt = 0; nt < 4; ++nt) {
        const int col = n0 + wn + nt * 16 + l15;
        const float bv = bias[col];
        #pragma unroll
        for (int mt = 0; mt < 4; ++mt) {
            const int rbase = m0 + wm + mt * 16 + quad * 4;
            #pragma unroll
            for (int r = 0; r < 4; ++r)
                out[(rbase + r) * OUT_F + col] = acc[mt][nt][r] + bv;
        }
    }
}

extern "C" void kernel_launch(void* const* d_in, const int* in_sizes, int n_in,
                              void* d_out, int out_size, void* d_ws, size_t ws_size,
                              hipStream_t stream)
{
    const float* x      = (const float*)d_in[0];  // (4096, 4096)
    const float* weight = (const float*)d_in[1];  // (4096, 4096)
    const float* bias   = (const float*)d_in[2];  // (4096,)
    float* out = (float*)d_out;                   // (4096, 4096) f32

    bf16* xs  = (bf16*)d_ws;                      // 4096*256 bf16 = 2 MB
    bf16* wsT = xs + 4096 * 256;                  // 4096*256 bf16 = 2 MB

    reduce_kernel<<<8192, 256, 0, stream>>>(x, weight, xs, wsT);
    gemm_bt_kernel<<<dim3(32, 32), 256, 0, stream>>>(xs, wsT, bias, out);
}

// Round 5
// 181.048 us; speedup vs baseline: 1.0637x; 1.0448x over previous
//
#include <hip/hip_runtime.h>

// Problem constants
#define H_ROWS 4096
#define IN_F   4096
#define OUT_F  4096

typedef __bf16 bf16;
typedef __bf16 bf16x4 __attribute__((ext_vector_type(4)));
typedef __bf16 bf16x8 __attribute__((ext_vector_type(8)));
typedef float  f32x4  __attribute__((ext_vector_type(4)));

// ---------------------------------------------------------------------------
// Kernel 1 (R8): R3 reduce body verbatim, split into two launches (x then w)
// purely so the gemm becomes visible in top-5 rocprof output (each half
// ~24-27 µs < gemm's plausible duration). Body is the proven 48 µs shape:
// fine-grained block retirement (4096 blocks/launch, backfill), 4 contiguous
// 4KB sweeps per thread, LDS tree finish. R4 post-mortem stands: wave-per-row
// regressed; per-wave ILP is a null lever. Do not touch the body.
// ---------------------------------------------------------------------------
__global__ __launch_bounds__(256) void reduce_half_kernel(
    const float* __restrict__ src, bf16* __restrict__ dst)
{
    __shared__ float lds[1024];
    const int r   = blockIdx.x;          // row 0..4095
    const int tid = threadIdx.x;

    const float4* __restrict__ s = (const float4*)src + r * (IN_F / 4);
    float4 a0 = s[tid];
    float4 a1 = s[tid + 256];
    float4 a2 = s[tid + 512];
    float4 a3 = s[tid + 768];
    float4 acc;
    acc.x = (a0.x + a1.x) + (a2.x + a3.x);
    acc.y = (a0.y + a1.y) + (a2.y + a3.y);
    acc.z = (a0.z + a1.z) + (a2.z + a3.z);
    acc.w = (a0.w + a1.w) + (a2.w + a3.w);

    ((float4*)lds)[tid] = acc;
    __syncthreads();

    if (tid < 64) {
        float4 b0 = ((const float4*)lds)[tid];
        float4 b1 = ((const float4*)lds)[tid + 64];
        float4 b2 = ((const float4*)lds)[tid + 128];
        float4 b3 = ((const float4*)lds)[tid + 192];
        float4 t;
        t.x = (b0.x + b1.x) + (b2.x + b3.x);
        t.y = (b0.y + b1.y) + (b2.y + b3.y);
        t.z = (b0.z + b1.z) + (b2.z + b3.z);
        t.w = (b0.w + b1.w) + (b2.w + b3.w);
        bf16x4 o;
        o[0] = (bf16)t.x; o[1] = (bf16)t.y; o[2] = (bf16)t.z; o[3] = (bf16)t.w;
        *(bf16x4*)(dst + r * 256 + tid * 4) = o;
    }
}

// ---------------------------------------------------------------------------
// Kernel 2 (R8): NT GEMM, dbuf BK=32 structure (R7, kept) + vectorized
// epilogue. Old epilogue: 64 scalar dword stores/thread in 64B row-segments.
// New: per mt-quadrant, stage acc into the (now free) 32KB staging LDS at
// f32 stride 132 (2-way bank aliasing = free on writes, 16B-aligned reads),
// then each half-wave stores 512B fully contiguous as dwordx4 (4x fewer
// store instructions, full-wave coalescing).
// ---------------------------------------------------------------------------
__global__ __launch_bounds__(256) void gemm_bt_kernel(
    const bf16* __restrict__ A, const bf16* __restrict__ B,
    const float* __restrict__ bias, float* __restrict__ out)
{
    __shared__ bf16 smem[16384];        // 32 KB: As[2] @ 0, Bs[2] @ 8192
    bf16* As = smem;                    // [2][128*32]
    bf16* Bs = smem + 8192;

    const int m0   = blockIdx.y * 128;
    const int n0   = blockIdx.x * 128;
    const int tid  = threadIdx.x;
    const int lane = tid & 63;
    const int w    = tid >> 6;
    const int wm   = (w & 1) * 64;
    const int wn   = (w >> 1) * 64;
    const int l15  = lane & 15;
    const int quad = lane >> 4;

    #define STAGE(b, kk)                                                      \
    {                                                                         \
        const int k0 = (kk) * 32;                                             \
        _Pragma("unroll")                                                     \
        for (int c = 0; c < 2; ++c) {                                         \
            const int chunk = c * 256 + tid;                                  \
            const int row   = chunk >> 2;                                     \
            const int kc    = chunk & 3;                                      \
            const bf16* ga = A + (m0 + row) * 256 + k0 + kc * 8;              \
            const bf16* gb = B + (n0 + row) * 256 + k0 + kc * 8;              \
            __builtin_amdgcn_global_load_lds(                                 \
                (const __attribute__((address_space(1))) void*)ga,            \
                (__attribute__((address_space(3))) void*)(As + (b) * 4096 + chunk * 8), \
                16, 0, 0);                                                    \
            __builtin_amdgcn_global_load_lds(                                 \
                (const __attribute__((address_space(1))) void*)gb,            \
                (__attribute__((address_space(3))) void*)(Bs + (b) * 4096 + chunk * 8), \
                16, 0, 0);                                                    \
        }                                                                     \
    }

    f32x4 acc[4][4] = {};

    STAGE(0, 0);

    int buf = 0;
    for (int kk = 0; kk < 8; ++kk) {
        __syncthreads();                       // staging(kk) visible; prev reads done
        if (kk < 7) STAGE(buf ^ 1, kk + 1);    // next-tile loads fly under MFMA

        bf16x8 af[4], bfr[4];
        #pragma unroll
        for (int t = 0; t < 4; ++t) {
            af[t]  = *(const bf16x8*)(As + buf * 4096 + (wm + t * 16 + l15) * 32 + quad * 8);
            bfr[t] = *(const bf16x8*)(Bs + buf * 4096 + (wn + t * 16 + l15) * 32 + quad * 8);
        }
        #pragma unroll
        for (int mt = 0; mt < 4; ++mt)
            #pragma unroll
            for (int nt = 0; nt < 4; ++nt)
                acc[mt][nt] = __builtin_amdgcn_mfma_f32_16x16x32_bf16(
                    af[mt], bfr[nt], acc[mt][nt], 0, 0, 0);
        buf ^= 1;
    }
    #undef STAGE

    // --- vectorized epilogue: repack each mt-quadrant (32 rows x 128 cols
    // f32, stride 132 = 16.9 KB) through the staging LDS, store dwordx4. ---
    float* sc = (float*)smem;
    const int w1 = w & 1;
    float bv[4];
    #pragma unroll
    for (int nt = 0; nt < 4; ++nt) bv[nt] = bias[n0 + wn + nt * 16 + l15];

    #pragma unroll
    for (int mt = 0; mt < 4; ++mt) {
        __syncthreads();                       // prior smem readers done
        #pragma unroll
        for (int nt = 0; nt < 4; ++nt) {
            const int col = wn + nt * 16 + l15;
            #pragma unroll
            for (int r = 0; r < 4; ++r)
                sc[(w1 * 16 + quad * 4 + r) * 132 + col] = acc[mt][nt][r] + bv[nt];
        }
        __syncthreads();
        #pragma unroll
        for (int i = 0; i < 4; ++i) {
            const int id   = i * 256 + tid;    // 0..1023 16B chunks
            const int lrow = id >> 5;          // 0..31 local row
            const int cc   = id & 31;          // chunk within row
            f32x4 v = *(const f32x4*)(sc + lrow * 132 + cc * 4);
            *(f32x4*)(out + (m0 + (lrow >> 4) * 64 + mt * 16 + (lrow & 15)) * OUT_F
                      + n0 + cc * 4) = v;
        }
    }
}

extern "C" void kernel_launch(void* const* d_in, const int* in_sizes, int n_in,
                              void* d_out, int out_size, void* d_ws, size_t ws_size,
                              hipStream_t stream)
{
    const float* x      = (const float*)d_in[0];  // (4096, 4096)
    const float* weight = (const float*)d_in[1];  // (4096, 4096)
    const float* bias   = (const float*)d_in[2];  // (4096,)
    float* out = (float*)d_out;                   // (4096, 4096) f32

    bf16* xs  = (bf16*)d_ws;                      // 4096*256 bf16 = 2 MB
    bf16* wsT = xs + 4096 * 256;                  // 4096*256 bf16 = 2 MB

    reduce_half_kernel<<<4096, 256, 0, stream>>>(x, xs);
    reduce_half_kernel<<<4096, 256, 0, stream>>>(weight, wsT);
    gemm_bt_kernel<<<dim3(32, 32), 256, 0, stream>>>(xs, wsT, bias, out);
}

// Round 7
// 168.906 us; speedup vs baseline: 1.1402x; 1.0719x over previous
//
#include <hip/hip_runtime.h>

// Problem constants
#define H_ROWS 4096
#define IN_F   4096
#define OUT_F  4096

typedef __bf16 bf16;
typedef __bf16 bf16x4 __attribute__((ext_vector_type(4)));
typedef __bf16 bf16x8 __attribute__((ext_vector_type(8)));
typedef float  f32x4  __attribute__((ext_vector_type(4)));

// ---------------------------------------------------------------------------
// Kernel 1 (R10 = R9 with the type fix): R3 geometry (single launch, 8192
// blocks, proven 48 µs) + ONE variable: non-temporal loads.
// __builtin_nontemporal_load requires a clang ext_vector pointer, not
// HIP_vector_type float4 — load via f32x4.
// Hypothesis: R8 showed the harness fill pushes 256 MiB through L2/L3 every
// iteration (thrashing Infinity Cache) while sustaining 6.6 TB/s writes; our
// reads blend HBM+cache to only 2.7 TB/s effective. nt bypasses L2/L3
// allocation on reads. Decisive either way: FETCH ~132 MB + time drop ->
// cache path was the limiter; time flat -> request-path ceiling, reduce
// closed at 48 µs. (R1-R4: geometry/ILP are null levers.)
// ---------------------------------------------------------------------------
__global__ __launch_bounds__(256) void reduce_kernel(
    const float* __restrict__ x, const float* __restrict__ w,
    bf16* __restrict__ xs, bf16* __restrict__ wsT)
{
    __shared__ float lds[1024];
    const int bid = blockIdx.x;
    const float* __restrict__ src = (bid & 1) ? w : x;
    bf16* __restrict__ dst = (bid & 1) ? wsT : xs;
    const int r   = bid >> 1;            // row 0..4095
    const int tid = threadIdx.x;

    const f32x4* __restrict__ s = (const f32x4*)src + r * (IN_F / 4);
    f32x4 a0 = __builtin_nontemporal_load(s + tid);
    f32x4 a1 = __builtin_nontemporal_load(s + tid + 256);
    f32x4 a2 = __builtin_nontemporal_load(s + tid + 512);
    f32x4 a3 = __builtin_nontemporal_load(s + tid + 768);
    f32x4 acc = (a0 + a1) + (a2 + a3);

    ((f32x4*)lds)[tid] = acc;
    __syncthreads();

    if (tid < 64) {
        f32x4 b0 = ((const f32x4*)lds)[tid];
        f32x4 b1 = ((const f32x4*)lds)[tid + 64];
        f32x4 b2 = ((const f32x4*)lds)[tid + 128];
        f32x4 b3 = ((const f32x4*)lds)[tid + 192];
        f32x4 t = (b0 + b1) + (b2 + b3);
        bf16x4 o;
        o[0] = (bf16)t[0]; o[1] = (bf16)t[1]; o[2] = (bf16)t[2]; o[3] = (bf16)t[3];
        *(bf16x4*)(dst + r * 256 + tid * 4) = o;
    }
}

// ---------------------------------------------------------------------------
// Kernel 2 (R8, unchanged): NT GEMM, dbuf BK=32 + LDS-repack dwordx4
// epilogue. R8 was the best measured total (181.0). Bounded < 41 µs (never
// in top-5); write-floor ~10 µs. Not the current lever.
// ---------------------------------------------------------------------------
__global__ __launch_bounds__(256) void gemm_bt_kernel(
    const bf16* __restrict__ A, const bf16* __restrict__ B,
    const float* __restrict__ bias, float* __restrict__ out)
{
    __shared__ bf16 smem[16384];        // 32 KB: As[2] @ 0, Bs[2] @ 8192
    bf16* As = smem;                    // [2][128*32]
    bf16* Bs = smem + 8192;

    const int m0   = blockIdx.y * 128;
    const int n0   = blockIdx.x * 128;
    const int tid  = threadIdx.x;
    const int lane = tid & 63;
    const int w    = tid >> 6;
    const int wm   = (w & 1) * 64;
    const int wn   = (w >> 1) * 64;
    const int l15  = lane & 15;
    const int quad = lane >> 4;

    #define STAGE(b, kk)                                                      \
    {                                                                         \
        const int k0 = (kk) * 32;                                             \
        _Pragma("unroll")                                                     \
        for (int c = 0; c < 2; ++c) {                                         \
            const int chunk = c * 256 + tid;                                  \
            const int row   = chunk >> 2;                                     \
            const int kc    = chunk & 3;                                      \
            const bf16* ga = A + (m0 + row) * 256 + k0 + kc * 8;              \
            const bf16* gb = B + (n0 + row) * 256 + k0 + kc * 8;              \
            __builtin_amdgcn_global_load_lds(                                 \
                (const __attribute__((address_space(1))) void*)ga,            \
                (__attribute__((address_space(3))) void*)(As + (b) * 4096 + chunk * 8), \
                16, 0, 0);                                                    \
            __builtin_amdgcn_global_load_lds(                                 \
                (const __attribute__((address_space(1))) void*)gb,            \
                (__attribute__((address_space(3))) void*)(Bs + (b) * 4096 + chunk * 8), \
                16, 0, 0);                                                    \
        }                                                                     \
    }

    f32x4 acc[4][4] = {};

    STAGE(0, 0);

    int buf = 0;
    for (int kk = 0; kk < 8; ++kk) {
        __syncthreads();                       // staging(kk) visible; prev reads done
        if (kk < 7) STAGE(buf ^ 1, kk + 1);    // next-tile loads fly under MFMA

        bf16x8 af[4], bfr[4];
        #pragma unroll
        for (int t = 0; t < 4; ++t) {
            af[t]  = *(const bf16x8*)(As + buf * 4096 + (wm + t * 16 + l15) * 32 + quad * 8);
            bfr[t] = *(const bf16x8*)(Bs + buf * 4096 + (wn + t * 16 + l15) * 32 + quad * 8);
        }
        #pragma unroll
        for (int mt = 0; mt < 4; ++mt)
            #pragma unroll
            for (int nt = 0; nt < 4; ++nt)
                acc[mt][nt] = __builtin_amdgcn_mfma_f32_16x16x32_bf16(
                    af[mt], bfr[nt], acc[mt][nt], 0, 0, 0);
        buf ^= 1;
    }
    #undef STAGE

    // Vectorized epilogue: repack each mt-quadrant (32 rows x 128 f32,
    // stride 132) through the staging LDS, store 16B dwordx4 contiguous.
    float* sc = (float*)smem;
    const int w1 = w & 1;
    float bv[4];
    #pragma unroll
    for (int nt = 0; nt < 4; ++nt) bv[nt] = bias[n0 + wn + nt * 16 + l15];

    #pragma unroll
    for (int mt = 0; mt < 4; ++mt) {
        __syncthreads();                       // prior smem readers done
        #pragma unroll
        for (int nt = 0; nt < 4; ++nt) {
            const int col = wn + nt * 16 + l15;
            #pragma unroll
            for (int r = 0; r < 4; ++r)
                sc[(w1 * 16 + quad * 4 + r) * 132 + col] = acc[mt][nt][r] + bv[nt];
        }
        __syncthreads();
        #pragma unroll
        for (int i = 0; i < 4; ++i) {
            const int id   = i * 256 + tid;    // 0..1023 16B chunks
            const int lrow = id >> 5;          // 0..31 local row
            const int cc   = id & 31;          // chunk within row
            f32x4 v = *(const f32x4*)(sc + lrow * 132 + cc * 4);
            *(f32x4*)(out + (m0 + (lrow >> 4) * 64 + mt * 16 + (lrow & 15)) * OUT_F
                      + n0 + cc * 4) = v;
        }
    }
}

extern "C" void kernel_launch(void* const* d_in, const int* in_sizes, int n_in,
                              void* d_out, int out_size, void* d_ws, size_t ws_size,
                              hipStream_t stream)
{
    const float* x      = (const float*)d_in[0];  // (4096, 4096)
    const float* weight = (const float*)d_in[1];  // (4096, 4096)
    const float* bias   = (const float*)d_in[2];  // (4096,)
    float* out = (float*)d_out;                   // (4096, 4096) f32

    bf16* xs  = (bf16*)d_ws;                      // 4096*256 bf16 = 2 MB
    bf16* wsT = xs + 4096 * 256;                  // 4096*256 bf16 = 2 MB

    reduce_kernel<<<8192, 256, 0, stream>>>(x, weight, xs, wsT);
    gemm_bt_kernel<<<dim3(32, 32), 256, 0, stream>>>(xs, wsT, bias, out);
}